// Round 17
// baseline (1439.654 us; speedup 1.0000x reference)
//
#include <hip/hip_runtime.h>

typedef unsigned short u16;
typedef unsigned int u32;
typedef unsigned char u8;

#define DD 256
#define PLCAP 1536

typedef short  s16x8 __attribute__((ext_vector_type(8)));
typedef short  s16x4 __attribute__((ext_vector_type(4)));
typedef float  f32x4 __attribute__((ext_vector_type(4)));
typedef float  f32x16 __attribute__((ext_vector_type(16)));

__device__ __forceinline__ float b2f(u16 u){
  union { u32 i; float f; } c; c.i = ((u32)u) << 16; return c.f;
}
// round-to-nearest-even f32 -> bf16 (finite inputs)
__device__ __forceinline__ u16 f2b(float f){
  union { float f; u32 i; } c; c.f = f;
  u32 b = c.i + 0x7FFFu + ((c.i >> 16) & 1u);
  return (u16)(b >> 16);
}

// keep the harness's expected symbol name alive
__global__ void NodeEncoder_72971494359603_kernel(){}

// ---------------- dtype probe ----------------
__global__ void probe_dtype(const u32* w, u32* flag){
  if (threadIdx.x == 0 && blockIdx.x == 0){
    int cnt = 0;
    for (int i = 0; i < 256; i++){
      u32 low = w[i] & 0xFFFFu;
      u32 e = (low >> 7) & 0xFFu;
      if (e >= 0x60u && e <= 0x7Eu) cnt++;
    }
    *flag = (cnt >= 192) ? 1u : 0u;
  }
}

// batched input conversion: 10 segments in one launch
struct CvtArgs {
  const void* src[10];
  u16* dst[10];
  int n[10];
};
__global__ void cvt_batch(CvtArgs a, const u32* __restrict__ flag){
  int i = blockIdx.x * 256 + threadIdx.x;
  u32 f = *flag;
#pragma unroll
  for (int s = 0; s < 10; s++){
    if (i < a.n[s]){
      if (f) a.dst[s][i] = ((const u16*)a.src[s])[i];
      else   a.dst[s][i] = f2b(((const float*)a.src[s])[i]);
      return;
    }
    i -= a.n[s];
  }
}

// ---------------- utility ----------------
__global__ void zero_int(int* p, int n){
  int i = blockIdx.x * 256 + threadIdx.x;
  if (i < n) p[i] = 0;
}

// TBL16[(l*18 + a*3 + b)*256 + j] = bf16(ee1[l][a][j] + ee2[l][b][j])
__global__ void build_table(const u16* ee1, const u16* ee2, u16* TBL){
  int b = blockIdx.x;               // 0..89
  int l = b / 18, c = b % 18, a = c / 3, bb = c % 3;
  int j = threadIdx.x;
  TBL[b * DD + j] = f2b(b2f(ee1[(l * 6 + a) * DD + j]) + b2f(ee2[(l * 3 + bb) * DD + j]));
}

// EMB9[c][j] = bf16(xe1[c/3][j] + xe2[c%3][j])  (x0,x1 in {0,1,2})
__global__ void build_emb9(const u16* xe1, const u16* xe2, u16* EMB9){
  int c = blockIdx.x;               // 0..8
  int j = threadIdx.x;
  EMB9[c * DD + j] = f2b(b2f(xe1[(c / 3) * DD + j]) + b2f(xe2[(c % 3) * DD + j]));
}

// per-node embedding code: x0*3 + x1 (clamped to {0,1,2})
__global__ void gen_codes(const int* x, u8* codes, int N){
  int n = blockIdx.x * 256 + threadIdx.x;
  if (n < N){
    int x0 = x[2 * n], x1 = x[2 * n + 1];
    x0 = x0 < 0 ? 0 : (x0 > 2 ? 2 : x0);
    x1 = x1 < 0 ? 0 : (x1 > 2 ? 2 : x1);
    codes[n] = (u8)(x0 * 3 + x1);
  }
}

// ---------------- CSR build ----------------
__global__ void hist_kernel(const int* dst, int* counts, int E){
  int e = blockIdx.x * 256 + threadIdx.x;
  if (e < E) atomicAdd(&counts[dst[e]], 1);
}

__global__ void scan_sums(const int* counts, int* bsum, int N){
  __shared__ int red[256];
  int tid = threadIdx.x;
  int base = blockIdx.x * 1024;
  int s = 0;
  for (int i = tid; i < 1024; i += 256){
    int g = base + i;
    if (g < N) s += counts[g];
  }
  red[tid] = s;
  __syncthreads();
  for (int off = 128; off > 0; off >>= 1){
    if (tid < off) red[tid] += red[tid + off];
    __syncthreads();
  }
  if (tid == 0) bsum[blockIdx.x] = red[0];
}

__global__ void scan_top(int* bsum, int nb){
  if (threadIdx.x == 0 && blockIdx.x == 0){
    int acc = 0;
    for (int i = 0; i < nb; i++){ int t = bsum[i]; bsum[i] = acc; acc += t; }
  }
}

__global__ void scan_block(const int* counts, const int* bsum,
                           int* offsets, int* cursor, int N){
  __shared__ int tsum[256];
  int b = blockIdx.x;
  int tid = threadIdx.x;
  int base = b * 1024;
  int v0, v1, v2, v3;
  int g = base + tid * 4;
  v0 = (g + 0 < N) ? counts[g + 0] : 0;
  v1 = (g + 1 < N) ? counts[g + 1] : 0;
  v2 = (g + 2 < N) ? counts[g + 2] : 0;
  v3 = (g + 3 < N) ? counts[g + 3] : 0;
  tsum[tid] = v0 + v1 + v2 + v3;
  __syncthreads();
  for (int off = 1; off < 256; off <<= 1){
    int t = (tid >= off) ? tsum[tid - off] : 0;
    __syncthreads();
    tsum[tid] += t;
    __syncthreads();
  }
  int excl = (tid == 0 ? 0 : tsum[tid - 1]) + bsum[b];
  if (g + 0 < N){ offsets[g + 0] = excl; cursor[g + 0] = excl; } excl += v0;
  if (g + 1 < N){ offsets[g + 1] = excl; cursor[g + 1] = excl; } excl += v1;
  if (g + 2 < N){ offsets[g + 2] = excl; cursor[g + 2] = excl; } excl += v2;
  if (g + 3 < N){ offsets[g + 3] = excl; cursor[g + 3] = excl; }
}

// payload[pos] = src | (idx << 17) | (code << 22)
__global__ void fill_csr(const int* ei, const int* ea, const int* x,
                         int* cursor, int* payload, int E){
  int e = blockIdx.x * 256 + threadIdx.x;
  if (e < E){
    int d = ei[E + e];
    int src = ei[e];
    int pos = atomicAdd(&cursor[d], 1);
    int a = ea[2 * e], bb = ea[2 * e + 1];
    int x0 = x[2 * src], x1 = x[2 * src + 1];
    x0 = x0 < 0 ? 0 : (x0 > 2 ? 2 : x0);
    x1 = x1 < 0 ? 0 : (x1 > 2 ? 2 : x1);
    payload[pos] = src | ((a * 3 + bb) << 17) | ((x0 * 3 + x1) << 22);
  }
}

// ---------------- B packing for 32x32x16 MFMA fragments ----------------
__global__ void pack_B(const u16* __restrict__ W0, u16* __restrict__ Wp0, int K, int Nc){
  const u16* W = W0 + (size_t)blockIdx.y * K * Nc;
  u16* Wp = Wp0 + (size_t)blockIdx.y * K * Nc;
  int idx = blockIdx.x * 256 + threadIdx.x;
  int lane = idx & 63;
  int t = idx >> 6;
  int nk = K >> 4;
  int kstep = t % nk, cblk = t / nk;
  if (cblk >= (Nc >> 5)) return;
  int col = cblk * 32 + (lane & 31);
  int krow = kstep * 16 + (lane >> 5) * 8;
  u16* dst = Wp + (size_t)idx * 8;
#pragma unroll
  for (int e = 0; e < 8; e++)
    dst[e] = W[(size_t)(krow + e) * Nc + col];
}

// ---------------- fused layer: gather(+BN+relu) -> MLP -> BN partials ----
// 64 nodes/block, 512 threads = 8 waves. Layer 0 (use_emb): LDS-only
// 9-entry embedding gather. Layers 1-4: the wave's 8 rows' edges are a
// CONTIGUOUS CSR range; edges processed in batches of 8 via
// global_load_lds (per-lane global src, linear LDS dest in the wave's
// own As region, dead until the output write) -> 8 rows in flight with
// ZERO landing VGPRs (registers were the ILP cap: rounds 13-15).
// Row attribution is wave-uniform with compile-time indices (rule #20).
// MLP: 32x32x16 MFMA, conflict-free As swizzle, Ms double-buffered.
__global__ __launch_bounds__(512, 4)
void layer_fused(const u16* __restrict__ feat, const u16* __restrict__ TBL,
                 const int* __restrict__ offsets, const int* __restrict__ counts,
                 const int* __restrict__ payload,
                 const u16* __restrict__ Wp1, const u16* __restrict__ bias1,
                 const u16* __restrict__ Wp2, const u16* __restrict__ bias2,
                 u16* __restrict__ H, float* __restrict__ partial, int npart, int M,
                 const float* __restrict__ sums, const u16* __restrict__ gamma,
                 const u16* __restrict__ beta, float invN, int apply_bn,
                 const u16* __restrict__ EMB9, const u8* __restrict__ codes, int use_emb,
                 void* __restrict__ dout, const u32* __restrict__ dflag){
  __shared__ __align__(16) u16 As[64 * 256];     // 32 KB
  __shared__ __align__(16) u16 Ms[2][64 * 128];  // 2 x 16 KB
  u16* T  = (u16*)Ms;                            // 9216 B table overlay
  u16* EM = (u16*)((char*)Ms + 9216);            // 4608 B emb9 overlay
  int* PL = (int*)((char*)Ms + 13824);           // 6144 B payload overlay
  int tid = threadIdx.x, lane = tid & 63, wave = tid >> 6;
  int wr = wave >> 2, wc = wave & 3;             // 2 x 4 wave grid
  int row0 = blockIdx.x * 64;
  int l31 = lane & 31, lhi = lane >> 5;          // 32x32 fragment coords

  // ---- stage bf16 TBL (+EMB9) + block payload slice into Ms overlay ----
  {
    u32* Tw = (u32*)T;
    const u32* Gw = (const u32*)TBL;
    for (int i = tid; i < 18 * DD / 2; i += 512) Tw[i] = Gw[i];
    if (use_emb){
      u32* Ew = (u32*)EM;
      const u32* Sw = (const u32*)EMB9;
      for (int i = tid; i < 9 * DD / 2; i += 512) Ew[i] = Sw[i];
    }
  }
  int nlast = row0 + 63; if (nlast > M - 1) nlast = M - 1;
  int e_start = offsets[row0];
  int e_total = offsets[nlast] + counts[nlast] - e_start;
  for (int i = tid; i < e_total && i < PLCAP; i += 512) PL[i] = payload[e_start + i];
  __syncthreads();

  // ---- phase 0: gather into As (wave handles rows wave*8 .. wave*8+7) ----
  if (use_emb){
    int c4 = lane * 4;
    s16x4 tb = *(const s16x4*)(T + 12 * DD + c4);
    for (int u = 0; u < 8; u++){
      int r = wave * 8 + u;
      int n = row0 + r; if (n > M - 1) n = M - 1;
      int cd = codes[n];
      s16x4 ev = *(const s16x4*)(EM + cd * DD + c4);
      float a0 = b2f((u16)ev[0]) + b2f((u16)tb[0]);
      float a1 = b2f((u16)ev[1]) + b2f((u16)tb[1]);
      float a2 = b2f((u16)ev[2]) + b2f((u16)tb[2]);
      float a3 = b2f((u16)ev[3]) + b2f((u16)tb[3]);
      int e0 = offsets[n], eend = e0 + counts[n];
      for (int e = e0; e < eend; e++){
        int idx = e - e_start;
        int pl = (idx < PLCAP) ? PL[idx] : payload[e];
        s16x4 rv = *(const s16x4*)(EM + ((pl >> 22) & 15) * DD + c4);
        s16x4 tv = *(const s16x4*)(T + ((pl >> 17) & 31) * DD + c4);
        a0 += b2f((u16)rv[0]) + b2f((u16)tv[0]);
        a1 += b2f((u16)rv[1]) + b2f((u16)tv[1]);
        a2 += b2f((u16)rv[2]) + b2f((u16)tv[2]);
        a3 += b2f((u16)rv[3]) + b2f((u16)tv[3]);
      }
      s16x4 o;
      o[0] = (short)f2b(a0); o[1] = (short)f2b(a1);
      o[2] = (short)f2b(a2); o[3] = (short)f2b(a3);
      int byteo = r * 512 + (((lane >> 1) ^ (r & 31)) << 4) + ((lane & 1) << 3);
      *(s16x4*)((char*)As + byteo) = o;
    }
  } else {
    int c4 = lane * 4;
    float sc[4], sh[4];
    if (apply_bn){
#pragma unroll
      for (int e = 0; e < 4; e++){
        int j = c4 + e;
        float mean = sums[j] * invN;
        float var = sums[DD + j] * invN - mean * mean;
        if (var < 0.f) var = 0.f;
        float scl = rsqrtf(var + 1e-5f) * b2f(gamma[j]);
        sc[e] = scl; sh[e] = b2f(beta[j]) - mean * scl;
      }
    } else {
#pragma unroll
      for (int e = 0; e < 4; e++){ sc[e] = 1.f; sh[e] = 0.f; }
    }
    int rbase = wave * 8;
    // hoist all 8 rows' metadata + self rows (concurrent loads)
    int offs[8], cnts[8]; s16x4 sv[8];
#pragma unroll
    for (int u = 0; u < 8; u++){
      int n = row0 + rbase + u; if (n > M - 1) n = M - 1;
      offs[u] = offsets[n]; cnts[u] = counts[n];
      sv[u] = *(const s16x4*)(feat + (size_t)n * DD + c4);
    }
    s16x4 tb = *(const s16x4*)(T + 12 * DD + c4);  // self-loop (4,0) -> idx 12

    // init accumulators from self rows
    float a[8][4];
#pragma unroll
    for (int h = 0; h < 8; h++){
      s16x4 svv = sv[h];
#pragma unroll
      for (int j = 0; j < 4; j++){
        float v = b2f((u16)svv[j]) * sc[j] + sh[j];
        if (apply_bn) v = fmaxf(v, 0.f);
        a[h][j] = v + b2f((u16)tb[j]);
      }
    }

    // ---- flattened edge range: batches of 8 rows via global_load_lds ----
    // staging = the wave's own As output region (4 KB, free until the
    // final write); slot i = stg + i*512, linear layout = wave-lane order.
    char* stg = (char*)As + wave * 4096;
    int e_lo = offs[0];
    int e_hi = offs[7] + cnts[7];
    int h = 0;                                   // wave-uniform current row
    for (int b0 = e_lo; b0 < e_hi; b0 += 8){
      int nb = e_hi - b0; if (nb > 8) nb = 8;
      int pls[8];
      // issue: 2 x 256B halves per edge row, fire-and-forget into LDS
#pragma unroll
      for (int i = 0; i < 8; i++){
        if (i < nb){
          int e = b0 + i;
          int idx = e - e_start;
          int pl = (idx < PLCAP) ? PL[idx] : payload[e];
          pls[i] = pl;
          const u32* gsrc = (const u32*)(feat + (size_t)(pl & 0x1FFFF) * DD);
          __builtin_amdgcn_global_load_lds(gsrc + lane, (u32*)(stg + i * 512), 4, 0, 0);
          __builtin_amdgcn_global_load_lds(gsrc + 64 + lane, (u32*)(stg + i * 512 + 256), 4, 0, 0);
        }
      }
      asm volatile("s_waitcnt vmcnt(0)" ::: "memory");
      // consume: row attribution is wave-uniform, compile-time indexed
#pragma unroll
      for (int i = 0; i < 8; i++){
        if (i < nb){
          int e = b0 + i;
#pragma unroll
          for (int hh = 0; hh < 7; hh++)
            if (h == hh && e >= offs[hh + 1]) h++;
          int pl = pls[i];
          s16x4 rv = *(const s16x4*)(stg + i * 512 + lane * 8);
          s16x4 tv = *(const s16x4*)(T + ((pl >> 17) & 31) * DD + c4);
          float w[4];
#pragma unroll
          for (int j = 0; j < 4; j++){
            float ww = b2f((u16)rv[j]) * sc[j] + sh[j];
            if (apply_bn) ww = fmaxf(ww, 0.f);
            w[j] = ww + b2f((u16)tv[j]);
          }
#pragma unroll
          for (int hh = 0; hh < 8; hh++)
            if (h == hh){
#pragma unroll
              for (int j = 0; j < 4; j++) a[hh][j] += w[j];
            }
        }
      }
    }

    // ---- write 8 rows to As (swizzled 8B stores; staging now dead) ----
#pragma unroll
    for (int hh = 0; hh < 8; hh++){
      int r = rbase + hh;
      s16x4 o;
      o[0] = (short)f2b(a[hh][0]); o[1] = (short)f2b(a[hh][1]);
      o[2] = (short)f2b(a[hh][2]); o[3] = (short)f2b(a[hh][3]);
      int byteo = r * 512 + (((lane >> 1) ^ (r & 31)) << 4) + ((lane & 1) << 3);
      *(s16x4*)((char*)As + byteo) = o;
    }
  }
  __syncthreads();   // As complete; T/EM/PL dead

  // ---- MLP: 4 chunks of 128 mid-cols, 32x32x16 MFMA ----
  f32x16 acc2[2];
#pragma unroll
  for (int n = 0; n < 2; n++)
#pragma unroll
    for (int i = 0; i < 16; i++) acc2[n][i] = 0.f;
  f32x16 acc1;

  auto G1 = [&](int cc){
    f32x16 a1;
#pragma unroll
    for (int i = 0; i < 16; i++) a1[i] = 0.f;
    int arow = wr * 32 + l31;
    int cb = cc * 4 + wc;                 // mid col-block of 32 (16 total)
#pragma unroll
    for (int ks = 0; ks < 16; ks++){
      int slot = (ks * 2 + lhi) ^ (arow & 31);
      s16x8 af = *(const s16x8*)((const char*)As + arow * 512 + (slot << 4));
      s16x8 bf = *(const s16x8*)(Wp1 + (((size_t)cb * 16 + ks) * 64 + lane) * 8);
      a1 = __builtin_amdgcn_mfma_f32_32x32x16_bf16(af, bf, a1, 0, 0, 0);
    }
    acc1 = a1;
  };
  auto WMS = [&](int cc, int buf){
    char* ms = (char*)Ms[buf];
    int col = wc * 32 + l31;
    float bv = b2f(bias1[cc * 128 + col]);
#pragma unroll
    for (int reg = 0; reg < 16; reg++){
      int mrow = wr * 32 + (reg & 3) + 8 * (reg >> 2) + 4 * lhi;
      float v = fmaxf(acc1[reg] + bv, 0.f);
      int slot = (col >> 3) ^ (mrow & 15);
      *(u16*)(ms + mrow * 256 + (slot << 4) + (col & 7) * 2) = f2b(v);
    }
  };

  G1(0);
  WMS(0, 0);
  __syncthreads();

#pragma unroll
  for (int c = 0; c < 4; c++){
    const char* ms = (const char*)Ms[c & 1];
    int mrow = wr * 32 + l31;
#pragma unroll
    for (int ks = 0; ks < 8; ks++){
      int slot = (ks * 2 + lhi) ^ (mrow & 15);
      s16x8 mf = *(const s16x8*)(ms + mrow * 256 + (slot << 4));
#pragma unroll
      for (int n = 0; n < 2; n++){
        int cb2 = wc * 2 + n;             // out col-block of 32 (8 total)
        s16x8 wf = *(const s16x8*)(Wp2 + (((size_t)cb2 * 32 + c * 8 + ks) * 64 + lane) * 8);
        acc2[n] = __builtin_amdgcn_mfma_f32_32x32x16_bf16(mf, wf, acc2[n], 0, 0, 0);
      }
    }
    if (c < 3){
      G1(c + 1);                    // overlaps with G2(c) in this region
      WMS(c + 1, (c + 1) & 1);      // writes the buffer not being read
      __syncthreads();
    }
  }

  // ---- epilogue: bias2 -> As bounce ----
#pragma unroll
  for (int n = 0; n < 2; n++){
    int col = wc * 64 + n * 32 + l31;
    float bv = b2f(bias2[col]);
#pragma unroll
    for (int reg = 0; reg < 16; reg++){
      int row = wr * 32 + (reg & 3) + 8 * (reg >> 2) + 4 * lhi;
      int slot = (col >> 3) ^ (row & 31);
      *(u16*)((char*)As + row * 512 + (slot << 4) + (col & 7) * 2) = f2b(acc2[n][reg] + bv);
    }
  }
  __syncthreads();

  // ---- readback: coalesced stores + BN partials ----
  float s[8], q[8];
#pragma unroll
  for (int e = 0; e < 8; e++){ s[e] = 0.f; q[e] = 0.f; }
  int sl = tid & 31;
  u32 df = dout ? *dflag : 0u;
#pragma unroll
  for (int p = 0; p < 4; p++){
    int r = p * 16 + (tid >> 5);
    s16x8 v = *(const s16x8*)((const char*)As + r * 512 + ((sl ^ (r & 31)) << 4));
    int gr = row0 + r;
    if (gr < M){
      if (dout){
        if (df){
          *(s16x8*)((u16*)dout + (size_t)gr * DD + sl * 8) = v;
        } else {
          f32x4 o0, o1;
#pragma unroll
          for (int e = 0; e < 4; e++){ o0[e] = b2f((u16)v[e]); o1[e] = b2f((u16)v[4 + e]); }
          *(f32x4*)((float*)dout + (size_t)gr * DD + sl * 8) = o0;
          *(f32x4*)((float*)dout + (size_t)gr * DD + sl * 8 + 4) = o1;
        }
      } else {
        *(s16x8*)(H + (size_t)gr * DD + sl * 8) = v;
      }
      if (partial){
#pragma unroll
        for (int e = 0; e < 8; e++){
          float f = b2f((u16)v[e]);
          s[e] += f; q[e] += f * f;
        }
      }
    }
  }
  if (partial){
#pragma unroll
    for (int e = 0; e < 8; e++){
      s[e] += __shfl_xor(s[e], 32);
      q[e] += __shfl_xor(q[e], 32);
    }
    __syncthreads();                     // all As/Ms reads done
    float* redS = (float*)Ms;            // 8x256 f32 = 8 KB
    float* redQ = redS + 8 * 256;        // 8x256 f32 = 8 KB (fits 32 KB Ms)
    if (lane < 32){
#pragma unroll
      for (int e = 0; e < 8; e++){
        redS[wave * 256 + sl * 8 + e] = s[e];
        redQ[wave * 256 + sl * 8 + e] = q[e];
      }
    }
    __syncthreads();
    if (tid < 256){
      float a = 0.f, b = 0.f;
#pragma unroll
      for (int w = 0; w < 8; w++){ a += redS[w * 256 + tid]; b += redQ[w * 256 + tid]; }
      partial[(size_t)blockIdx.x * DD + tid] = a;
      partial[(size_t)(npart + blockIdx.x) * DD + tid] = b;
    }
  }
}

// ---------------- BN reduce: sums[which][j] = sum over npart partials ----
__global__ void bn_reduce(const float* __restrict__ partial, float* __restrict__ sums,
                          int npart){
  int b = blockIdx.x, which = b >> 3, jg = b & 7;  // grid = 16
  int t = threadIdx.x;
  int j = jg * 32 + (t >> 3);
  int li = t & 7;
  float s = 0.f;
  for (int i = li; i < npart; i += 8)
    s += partial[(size_t)(which * npart + i) * DD + j];
  s += __shfl_xor(s, 1); s += __shfl_xor(s, 2); s += __shfl_xor(s, 4);
  if (li == 0) sums[which * DD + j] = s;
}

// ---------------- host ----------------
extern "C" void kernel_launch(void* const* d_in, const int* in_sizes, int n_in,
                              void* d_out, int out_size, void* d_ws, size_t ws_size,
                              hipStream_t stream){
  (void)n_in; (void)out_size; (void)ws_size;
  const int* x    = (const int*)d_in[0];
  const int* ei   = (const int*)d_in[1];
  const int* ea   = (const int*)d_in[2];
  const void* xe1 = d_in[3];
  const void* xe2 = d_in[4];
  const void* ee1 = d_in[5];
  const void* ee2 = d_in[6];
  const void* W1  = d_in[7];
  const void* b1  = d_in[8];
  const void* W2  = d_in[9];
  const void* b2  = d_in[10];
  const void* gam = d_in[11];
  const void* bet = d_in[12];

  int N = in_sizes[0] / 2;
  int E = in_sizes[1] / 2;
  int NB = (N + 1023) / 1024;
  const int L = 5;
  int nblk = (N + 63) / 64;        // fused-layer blocks
  int npart = nblk;                // BN partials (one per block)

  // manual workspace carve (256B aligned)
  char* base = (char*)d_ws;
  size_t off = 0;
  u32* flag    = (u32*)(base + off);   off += 256;
  u16* TBL     = (u16*)(base + off);   off += ((size_t)L * 18 * DD * 2 + 255) & ~(size_t)255;
  u16* EMB9    = (u16*)(base + off);   off += ((size_t)9 * DD * 2 + 255) & ~(size_t)255;
  u8* codes    = (u8*)(base + off);    off += ((size_t)N + 255) & ~(size_t)255;
  int* counts  = (int*)(base + off);   off += ((size_t)N * 4 + 255) & ~(size_t)255;
  int* offsets = (int*)(base + off);   off += ((size_t)N * 4 + 255) & ~(size_t)255;
  int* cursor  = (int*)(base + off);   off += ((size_t)N * 4 + 255) & ~(size_t)255;
  int* bsum    = (int*)(base + off);   off += ((size_t)NB * 4 + 255) & ~(size_t)255;
  int* payload = (int*)(base + off);   off += ((size_t)E * 4 + 255) & ~(size_t)255;
  float* part  = (float*)(base + off); off += ((size_t)2 * npart * DD * 4 + 255) & ~(size_t)255;
  float* sums  = (float*)(base + off); off += ((size_t)2 * DD * 4 + 255) & ~(size_t)255;
  // bf16 working copies of float inputs
  u16* wx1  = (u16*)(base + off); off += ((size_t)120 * DD * 2 + 255) & ~(size_t)255;
  u16* wx2  = (u16*)(base + off); off += ((size_t)3 * DD * 2 + 255) & ~(size_t)255;
  u16* wee1 = (u16*)(base + off); off += ((size_t)L * 6 * DD * 2 + 255) & ~(size_t)255;
  u16* wee2 = (u16*)(base + off); off += ((size_t)L * 3 * DD * 2 + 255) & ~(size_t)255;
  u16* wW1  = (u16*)(base + off); off += ((size_t)L * DD * 2 * DD * 2 + 255) & ~(size_t)255;
  u16* wb1  = (u16*)(base + off); off += ((size_t)L * 2 * DD * 2 + 255) & ~(size_t)255;
  u16* wW2  = (u16*)(base + off); off += ((size_t)L * 2 * DD * DD * 2 + 255) & ~(size_t)255;
  u16* wb2  = (u16*)(base + off); off += ((size_t)L * DD * 2 + 255) & ~(size_t)255;
  u16* wgam = (u16*)(base + off); off += ((size_t)(L - 1) * DD * 2 + 255) & ~(size_t)255;
  u16* wbet = (u16*)(base + off); off += ((size_t)(L - 1) * DD * 2 + 255) & ~(size_t)255;
  // packed MFMA B fragments
  u16* Wp1  = (u16*)(base + off); off += ((size_t)L * DD * 2 * DD * 2 + 255) & ~(size_t)255;
  u16* Wp2  = (u16*)(base + off); off += ((size_t)L * 2 * DD * DD * 2 + 255) & ~(size_t)255;
  // ping-pong feature buffers (bf16)
  u16* featA = (u16*)(base + off); off += ((size_t)N * DD * 2 + 255) & ~(size_t)255;
  u16* featB = (u16*)(base + off); off += ((size_t)N * DD * 2 + 255) & ~(size_t)255;

  // dtype probe + batched input conversion to bf16 working copies
  probe_dtype<<<1, 64, 0, stream>>>((const u32*)xe1, flag);
  {
    CvtArgs ca;
    const void* srcs[10] = { xe1, xe2, ee1, ee2, W1, b1, W2, b2, gam, bet };
    u16* dsts[10] = { wx1, wx2, wee1, wee2, wW1, wb1, wW2, wb2, wgam, wbet };
    int ns[10] = { 120 * DD, 3 * DD, L * 6 * DD, L * 3 * DD, L * DD * 2 * DD,
                   L * 2 * DD, L * 2 * DD * DD, L * DD, (L - 1) * DD, (L - 1) * DD };
    int total = 0;
    for (int i = 0; i < 10; i++){ ca.src[i] = srcs[i]; ca.dst[i] = dsts[i]; ca.n[i] = ns[i]; total += ns[i]; }
    cvt_batch<<<(total + 255) / 256, 256, 0, stream>>>(ca, flag);
  }

  // one-time per call: tables, packed weights (batched), CSR
  build_table<<<90, 256, 0, stream>>>(wee1, wee2, TBL);
  build_emb9<<<9, 256, 0, stream>>>(wx1, wx2, EMB9);
  gen_codes<<<(N + 255) / 256, 256, 0, stream>>>(x, codes, N);
  pack_B<<<dim3(64, L), 256, 0, stream>>>(wW1, Wp1, DD, 2 * DD);
  pack_B<<<dim3(64, L), 256, 0, stream>>>(wW2, Wp2, 2 * DD, DD);
  zero_int<<<(N + 255) / 256, 256, 0, stream>>>(counts, N);
  hist_kernel<<<(E + 255) / 256, 256, 0, stream>>>(ei + E, counts, E);
  scan_sums<<<NB, 256, 0, stream>>>(counts, bsum, N);
  scan_top<<<1, 64, 0, stream>>>(bsum, NB);
  scan_block<<<NB, 256, 0, stream>>>(counts, bsum, offsets, cursor, N);
  fill_csr<<<(E + 255) / 256, 256, 0, stream>>>(ei, ea, x, cursor, payload, E);

  float invN = 1.0f / (float)N;
  u16* fin = featA;
  u16* fout = featB;

  for (int l = 0; l < L; l++){
    int last = (l == L - 1);
    layer_fused<<<nblk, 512, 0, stream>>>(
        fin, TBL + (size_t)l * 18 * DD, offsets, counts, payload,
        Wp1 + (size_t)l * DD * 2 * DD, wb1 + (size_t)l * 2 * DD,
        Wp2 + (size_t)l * 2 * DD * DD, wb2 + (size_t)l * DD,
        fout, (l < L - 1) ? part : (float*)nullptr, npart, N,
        sums, wgam + (size_t)(l > 0 ? l - 1 : 0) * DD,
        wbet + (size_t)(l > 0 ? l - 1 : 0) * DD, invN, l > 0 ? 1 : 0,
        EMB9, codes, l == 0 ? 1 : 0,
        last ? d_out : (void*)nullptr, flag);

    if (l < L - 1){
      bn_reduce<<<16, 256, 0, stream>>>(part, sums, npart);
    }
    u16* t = fin; fin = fout; fout = t;
  }
}

// Round 18
// 1358.549 us; speedup vs baseline: 1.0597x; 1.0597x over previous
//
#include <hip/hip_runtime.h>

typedef unsigned short u16;
typedef unsigned int u32;
typedef unsigned char u8;

#define DD 256
#define PLCAP 1536

typedef short  s16x8 __attribute__((ext_vector_type(8)));
typedef short  s16x4 __attribute__((ext_vector_type(4)));
typedef float  f32x4 __attribute__((ext_vector_type(4)));
typedef float  f32x16 __attribute__((ext_vector_type(16)));

__device__ __forceinline__ float b2f(u16 u){
  union { u32 i; float f; } c; c.i = ((u32)u) << 16; return c.f;
}
// round-to-nearest-even f32 -> bf16 (finite inputs)
__device__ __forceinline__ u16 f2b(float f){
  union { float f; u32 i; } c; c.f = f;
  u32 b = c.i + 0x7FFFu + ((c.i >> 16) & 1u);
  return (u16)(b >> 16);
}

// keep the harness's expected symbol name alive
__global__ void NodeEncoder_72971494359603_kernel(){}

// ---------------- dtype probe ----------------
__global__ void probe_dtype(const u32* w, u32* flag){
  if (threadIdx.x == 0 && blockIdx.x == 0){
    int cnt = 0;
    for (int i = 0; i < 256; i++){
      u32 low = w[i] & 0xFFFFu;
      u32 e = (low >> 7) & 0xFFu;
      if (e >= 0x60u && e <= 0x7Eu) cnt++;
    }
    *flag = (cnt >= 192) ? 1u : 0u;
  }
}

// batched input conversion: 10 segments in one launch
struct CvtArgs {
  const void* src[10];
  u16* dst[10];
  int n[10];
};
__global__ void cvt_batch(CvtArgs a, const u32* __restrict__ flag){
  int i = blockIdx.x * 256 + threadIdx.x;
  u32 f = *flag;
#pragma unroll
  for (int s = 0; s < 10; s++){
    if (i < a.n[s]){
      if (f) a.dst[s][i] = ((const u16*)a.src[s])[i];
      else   a.dst[s][i] = f2b(((const float*)a.src[s])[i]);
      return;
    }
    i -= a.n[s];
  }
}

// ---------------- utility ----------------
__global__ void zero_int(int* p, int n){
  int i = blockIdx.x * 256 + threadIdx.x;
  if (i < n) p[i] = 0;
}

// TBL16[(l*18 + a*3 + b)*256 + j] = bf16(ee1[l][a][j] + ee2[l][b][j])
__global__ void build_table(const u16* ee1, const u16* ee2, u16* TBL){
  int b = blockIdx.x;               // 0..89
  int l = b / 18, c = b % 18, a = c / 3, bb = c % 3;
  int j = threadIdx.x;
  TBL[b * DD + j] = f2b(b2f(ee1[(l * 6 + a) * DD + j]) + b2f(ee2[(l * 3 + bb) * DD + j]));
}

// EMB9[c][j] = bf16(xe1[c/3][j] + xe2[c%3][j])  (x0,x1 in {0,1,2})
__global__ void build_emb9(const u16* xe1, const u16* xe2, u16* EMB9){
  int c = blockIdx.x;               // 0..8
  int j = threadIdx.x;
  EMB9[c * DD + j] = f2b(b2f(xe1[(c / 3) * DD + j]) + b2f(xe2[(c % 3) * DD + j]));
}

// per-node embedding code: x0*3 + x1 (clamped to {0,1,2})
__global__ void gen_codes(const int* x, u8* codes, int N){
  int n = blockIdx.x * 256 + threadIdx.x;
  if (n < N){
    int x0 = x[2 * n], x1 = x[2 * n + 1];
    x0 = x0 < 0 ? 0 : (x0 > 2 ? 2 : x0);
    x1 = x1 < 0 ? 0 : (x1 > 2 ? 2 : x1);
    codes[n] = (u8)(x0 * 3 + x1);
  }
}

// ---------------- CSR build ----------------
__global__ void hist_kernel(const int* dst, int* counts, int E){
  int e = blockIdx.x * 256 + threadIdx.x;
  if (e < E) atomicAdd(&counts[dst[e]], 1);
}

__global__ void scan_sums(const int* counts, int* bsum, int N){
  __shared__ int red[256];
  int tid = threadIdx.x;
  int base = blockIdx.x * 1024;
  int s = 0;
  for (int i = tid; i < 1024; i += 256){
    int g = base + i;
    if (g < N) s += counts[g];
  }
  red[tid] = s;
  __syncthreads();
  for (int off = 128; off > 0; off >>= 1){
    if (tid < off) red[tid] += red[tid + off];
    __syncthreads();
  }
  if (tid == 0) bsum[blockIdx.x] = red[0];
}

__global__ void scan_top(int* bsum, int nb){
  if (threadIdx.x == 0 && blockIdx.x == 0){
    int acc = 0;
    for (int i = 0; i < nb; i++){ int t = bsum[i]; bsum[i] = acc; acc += t; }
  }
}

__global__ void scan_block(const int* counts, const int* bsum,
                           int* offsets, int* cursor, int N){
  __shared__ int tsum[256];
  int b = blockIdx.x;
  int tid = threadIdx.x;
  int base = b * 1024;
  int v0, v1, v2, v3;
  int g = base + tid * 4;
  v0 = (g + 0 < N) ? counts[g + 0] : 0;
  v1 = (g + 1 < N) ? counts[g + 1] : 0;
  v2 = (g + 2 < N) ? counts[g + 2] : 0;
  v3 = (g + 3 < N) ? counts[g + 3] : 0;
  tsum[tid] = v0 + v1 + v2 + v3;
  __syncthreads();
  for (int off = 1; off < 256; off <<= 1){
    int t = (tid >= off) ? tsum[tid - off] : 0;
    __syncthreads();
    tsum[tid] += t;
    __syncthreads();
  }
  int excl = (tid == 0 ? 0 : tsum[tid - 1]) + bsum[b];
  if (g + 0 < N){ offsets[g + 0] = excl; cursor[g + 0] = excl; } excl += v0;
  if (g + 1 < N){ offsets[g + 1] = excl; cursor[g + 1] = excl; } excl += v1;
  if (g + 2 < N){ offsets[g + 2] = excl; cursor[g + 2] = excl; } excl += v2;
  if (g + 3 < N){ offsets[g + 3] = excl; cursor[g + 3] = excl; }
}

// payload[pos] = src | (idx << 17) | (code << 22)
__global__ void fill_csr(const int* ei, const int* ea, const int* x,
                         int* cursor, int* payload, int E){
  int e = blockIdx.x * 256 + threadIdx.x;
  if (e < E){
    int d = ei[E + e];
    int src = ei[e];
    int pos = atomicAdd(&cursor[d], 1);
    int a = ea[2 * e], bb = ea[2 * e + 1];
    int x0 = x[2 * src], x1 = x[2 * src + 1];
    x0 = x0 < 0 ? 0 : (x0 > 2 ? 2 : x0);
    x1 = x1 < 0 ? 0 : (x1 > 2 ? 2 : x1);
    payload[pos] = src | ((a * 3 + bb) << 17) | ((x0 * 3 + x1) << 22);
  }
}

// ---------------- B packing for 32x32x16 MFMA fragments ----------------
__global__ void pack_B(const u16* __restrict__ W0, u16* __restrict__ Wp0, int K, int Nc){
  const u16* W = W0 + (size_t)blockIdx.y * K * Nc;
  u16* Wp = Wp0 + (size_t)blockIdx.y * K * Nc;
  int idx = blockIdx.x * 256 + threadIdx.x;
  int lane = idx & 63;
  int t = idx >> 6;
  int nk = K >> 4;
  int kstep = t % nk, cblk = t / nk;
  if (cblk >= (Nc >> 5)) return;
  int col = cblk * 32 + (lane & 31);
  int krow = kstep * 16 + (lane >> 5) * 8;
  u16* dst = Wp + (size_t)idx * 8;
#pragma unroll
  for (int e = 0; e < 8; e++)
    dst[e] = W[(size_t)(krow + e) * Nc + col];
}

// ---------------- fused layer: gather(+BN+relu) -> MLP -> BN partials ----
// Round-13 structure (verified best, no spills): 64 nodes/block, 512
// threads = 8 waves. Layer 0 (use_emb): LDS-only 9-entry embedding
// gather. Layers 1-4: 4-row x 4-edge interleaved gather (fits 64 VGPR;
// 8-row register burst spills (r14/15); LDS-staged gather adds VALU
// attribution + vmcnt drain overhead (r17) — both regress).
// MLP: 32x32x16 MFMA, conflict-free As swizzle, Ms double-buffered.
// Final layer writes d_out directly (bf16/f32 per dflag).
__global__ __launch_bounds__(512, 4)
void layer_fused(const u16* __restrict__ feat, const u16* __restrict__ TBL,
                 const int* __restrict__ offsets, const int* __restrict__ counts,
                 const int* __restrict__ payload,
                 const u16* __restrict__ Wp1, const u16* __restrict__ bias1,
                 const u16* __restrict__ Wp2, const u16* __restrict__ bias2,
                 u16* __restrict__ H, float* __restrict__ partial, int npart, int M,
                 const float* __restrict__ sums, const u16* __restrict__ gamma,
                 const u16* __restrict__ beta, float invN, int apply_bn,
                 const u16* __restrict__ EMB9, const u8* __restrict__ codes, int use_emb,
                 void* __restrict__ dout, const u32* __restrict__ dflag){
  __shared__ __align__(16) u16 As[64 * 256];     // 32 KB
  __shared__ __align__(16) u16 Ms[2][64 * 128];  // 2 x 16 KB
  u16* T  = (u16*)Ms;                            // 9216 B table overlay
  u16* EM = (u16*)((char*)Ms + 9216);            // 4608 B emb9 overlay
  int* PL = (int*)((char*)Ms + 13824);           // 6144 B payload overlay
  int tid = threadIdx.x, lane = tid & 63, wave = tid >> 6;
  int wr = wave >> 2, wc = wave & 3;             // 2 x 4 wave grid
  int row0 = blockIdx.x * 64;
  int l31 = lane & 31, lhi = lane >> 5;          // 32x32 fragment coords

  // ---- stage bf16 TBL (+EMB9) + block payload slice into Ms overlay ----
  {
    u32* Tw = (u32*)T;
    const u32* Gw = (const u32*)TBL;
    for (int i = tid; i < 18 * DD / 2; i += 512) Tw[i] = Gw[i];
    if (use_emb){
      u32* Ew = (u32*)EM;
      const u32* Sw = (const u32*)EMB9;
      for (int i = tid; i < 9 * DD / 2; i += 512) Ew[i] = Sw[i];
    }
  }
  int nlast = row0 + 63; if (nlast > M - 1) nlast = M - 1;
  int e_start = offsets[row0];
  int e_total = offsets[nlast] + counts[nlast] - e_start;
  for (int i = tid; i < e_total && i < PLCAP; i += 512) PL[i] = payload[e_start + i];
  __syncthreads();

  // ---- phase 0: gather into As (wave handles rows wave*8 .. wave*8+7) ----
  if (use_emb){
    int c4 = lane * 4;
    s16x4 tb = *(const s16x4*)(T + 12 * DD + c4);
    for (int u = 0; u < 8; u++){
      int r = wave * 8 + u;
      int n = row0 + r; if (n > M - 1) n = M - 1;
      int cd = codes[n];
      s16x4 ev = *(const s16x4*)(EM + cd * DD + c4);
      float a0 = b2f((u16)ev[0]) + b2f((u16)tb[0]);
      float a1 = b2f((u16)ev[1]) + b2f((u16)tb[1]);
      float a2 = b2f((u16)ev[2]) + b2f((u16)tb[2]);
      float a3 = b2f((u16)ev[3]) + b2f((u16)tb[3]);
      int e0 = offsets[n], eend = e0 + counts[n];
      for (int e = e0; e < eend; e++){
        int idx = e - e_start;
        int pl = (idx < PLCAP) ? PL[idx] : payload[e];
        s16x4 rv = *(const s16x4*)(EM + ((pl >> 22) & 15) * DD + c4);
        s16x4 tv = *(const s16x4*)(T + ((pl >> 17) & 31) * DD + c4);
        a0 += b2f((u16)rv[0]) + b2f((u16)tv[0]);
        a1 += b2f((u16)rv[1]) + b2f((u16)tv[1]);
        a2 += b2f((u16)rv[2]) + b2f((u16)tv[2]);
        a3 += b2f((u16)rv[3]) + b2f((u16)tv[3]);
      }
      s16x4 o;
      o[0] = (short)f2b(a0); o[1] = (short)f2b(a1);
      o[2] = (short)f2b(a2); o[3] = (short)f2b(a3);
      int byteo = r * 512 + (((lane >> 1) ^ (r & 31)) << 4) + ((lane & 1) << 3);
      *(s16x4*)((char*)As + byteo) = o;
    }
  } else {
    int c4 = lane * 4;
    float sc[4], sh[4];
    if (apply_bn){
#pragma unroll
      for (int e = 0; e < 4; e++){
        int j = c4 + e;
        float mean = sums[j] * invN;
        float var = sums[DD + j] * invN - mean * mean;
        if (var < 0.f) var = 0.f;
        float scl = rsqrtf(var + 1e-5f) * b2f(gamma[j]);
        sc[e] = scl; sh[e] = b2f(beta[j]) - mean * scl;
      }
    } else {
#pragma unroll
      for (int e = 0; e < 4; e++){ sc[e] = 1.f; sh[e] = 0.f; }
    }
    int rbase = wave * 8;
    // hoist all 8 rows' metadata + self rows (24 concurrent loads)
    int offs[8], cnts[8]; s16x4 sv[8];
#pragma unroll
    for (int u = 0; u < 8; u++){
      int n = row0 + rbase + u; if (n > M - 1) n = M - 1;
      offs[u] = offsets[n]; cnts[u] = counts[n];
      sv[u] = *(const s16x4*)(feat + (size_t)n * DD + c4);
    }
    s16x4 tb = *(const s16x4*)(T + 12 * DD + c4);  // self-loop (4,0) -> idx 12
#pragma unroll
    for (int up = 0; up < 2; up++){
      float a[4][4];
#pragma unroll
      for (int h = 0; h < 4; h++){
        s16x4 svv = sv[up * 4 + h];
#pragma unroll
        for (int j = 0; j < 4; j++){
          float v = b2f((u16)svv[j]) * sc[j] + sh[j];
          if (apply_bn) v = fmaxf(v, 0.f);
          a[h][j] = v + b2f((u16)tb[j]);
        }
      }
      int eo[4], cn[4], ii[4];
#pragma unroll
      for (int h = 0; h < 4; h++){
        eo[h] = offs[up * 4 + h]; cn[h] = cnts[up * 4 + h]; ii[h] = 0;
      }
      while (ii[0] < cn[0] || ii[1] < cn[1] || ii[2] < cn[2] || ii[3] < cn[3]){
        int bb[4]; int pls[4][4]; s16x4 rv[4][4];
#pragma unroll
        for (int h = 0; h < 4; h++){
          int t = cn[h] - ii[h];
          bb[h] = t > 4 ? 4 : (t < 0 ? 0 : t);
        }
#pragma unroll
        for (int h = 0; h < 4; h++)
#pragma unroll
          for (int i = 0; i < 4; i++)
            if (i < bb[h]){
              int idx = eo[h] + ii[h] + i - e_start;
              pls[h][i] = (idx < PLCAP) ? PL[idx] : payload[eo[h] + ii[h] + i];
            }
        // issue all rows' feat gathers back-to-back (up to 16 in flight)
#pragma unroll
        for (int h = 0; h < 4; h++)
#pragma unroll
          for (int i = 0; i < 4; i++)
            if (i < bb[h])
              rv[h][i] = *(const s16x4*)(feat + (size_t)(pls[h][i] & 0x1FFFF) * DD + c4);
        // consume
#pragma unroll
        for (int h = 0; h < 4; h++)
#pragma unroll
          for (int i = 0; i < 4; i++)
            if (i < bb[h]){
              s16x4 tv = *(const s16x4*)(T + ((pls[h][i] >> 17) & 31) * DD + c4);
#pragma unroll
              for (int j = 0; j < 4; j++){
                float w = b2f((u16)rv[h][i][j]) * sc[j] + sh[j];
                if (apply_bn) w = fmaxf(w, 0.f);
                a[h][j] += w + b2f((u16)tv[j]);
              }
            }
#pragma unroll
        for (int h = 0; h < 4; h++) ii[h] += bb[h];
      }
      // write 4 rows to As (swizzled 8B stores)
#pragma unroll
      for (int h = 0; h < 4; h++){
        int r = rbase + up * 4 + h;
        s16x4 o;
        o[0] = (short)f2b(a[h][0]); o[1] = (short)f2b(a[h][1]);
        o[2] = (short)f2b(a[h][2]); o[3] = (short)f2b(a[h][3]);
        int byteo = r * 512 + (((lane >> 1) ^ (r & 31)) << 4) + ((lane & 1) << 3);
        *(s16x4*)((char*)As + byteo) = o;
      }
    }
  }
  __syncthreads();   // As complete; T/EM/PL dead

  // ---- MLP: 4 chunks of 128 mid-cols, 32x32x16 MFMA ----
  f32x16 acc2[2];
#pragma unroll
  for (int n = 0; n < 2; n++)
#pragma unroll
    for (int i = 0; i < 16; i++) acc2[n][i] = 0.f;
  f32x16 acc1;

  auto G1 = [&](int cc){
    f32x16 a1;
#pragma unroll
    for (int i = 0; i < 16; i++) a1[i] = 0.f;
    int arow = wr * 32 + l31;
    int cb = cc * 4 + wc;                 // mid col-block of 32 (16 total)
#pragma unroll
    for (int ks = 0; ks < 16; ks++){
      int slot = (ks * 2 + lhi) ^ (arow & 31);
      s16x8 af = *(const s16x8*)((const char*)As + arow * 512 + (slot << 4));
      s16x8 bf = *(const s16x8*)(Wp1 + (((size_t)cb * 16 + ks) * 64 + lane) * 8);
      a1 = __builtin_amdgcn_mfma_f32_32x32x16_bf16(af, bf, a1, 0, 0, 0);
    }
    acc1 = a1;
  };
  auto WMS = [&](int cc, int buf){
    char* ms = (char*)Ms[buf];
    int col = wc * 32 + l31;
    float bv = b2f(bias1[cc * 128 + col]);
#pragma unroll
    for (int reg = 0; reg < 16; reg++){
      int mrow = wr * 32 + (reg & 3) + 8 * (reg >> 2) + 4 * lhi;
      float v = fmaxf(acc1[reg] + bv, 0.f);
      int slot = (col >> 3) ^ (mrow & 15);
      *(u16*)(ms + mrow * 256 + (slot << 4) + (col & 7) * 2) = f2b(v);
    }
  };

  G1(0);
  WMS(0, 0);
  __syncthreads();

#pragma unroll
  for (int c = 0; c < 4; c++){
    const char* ms = (const char*)Ms[c & 1];
    int mrow = wr * 32 + l31;
#pragma unroll
    for (int ks = 0; ks < 8; ks++){
      int slot = (ks * 2 + lhi) ^ (mrow & 15);
      s16x8 mf = *(const s16x8*)(ms + mrow * 256 + (slot << 4));
#pragma unroll
      for (int n = 0; n < 2; n++){
        int cb2 = wc * 2 + n;             // out col-block of 32 (8 total)
        s16x8 wf = *(const s16x8*)(Wp2 + (((size_t)cb2 * 32 + c * 8 + ks) * 64 + lane) * 8);
        acc2[n] = __builtin_amdgcn_mfma_f32_32x32x16_bf16(mf, wf, acc2[n], 0, 0, 0);
      }
    }
    if (c < 3){
      G1(c + 1);                    // overlaps with G2(c) in this region
      WMS(c + 1, (c + 1) & 1);      // writes the buffer not being read
      __syncthreads();
    }
  }

  // ---- epilogue: bias2 -> As bounce ----
#pragma unroll
  for (int n = 0; n < 2; n++){
    int col = wc * 64 + n * 32 + l31;
    float bv = b2f(bias2[col]);
#pragma unroll
    for (int reg = 0; reg < 16; reg++){
      int row = wr * 32 + (reg & 3) + 8 * (reg >> 2) + 4 * lhi;
      int slot = (col >> 3) ^ (row & 31);
      *(u16*)((char*)As + row * 512 + (slot << 4) + (col & 7) * 2) = f2b(acc2[n][reg] + bv);
    }
  }
  __syncthreads();

  // ---- readback: coalesced stores + BN partials ----
  float s[8], q[8];
#pragma unroll
  for (int e = 0; e < 8; e++){ s[e] = 0.f; q[e] = 0.f; }
  int sl = tid & 31;
  u32 df = dout ? *dflag : 0u;
#pragma unroll
  for (int p = 0; p < 4; p++){
    int r = p * 16 + (tid >> 5);
    s16x8 v = *(const s16x8*)((const char*)As + r * 512 + ((sl ^ (r & 31)) << 4));
    int gr = row0 + r;
    if (gr < M){
      if (dout){
        if (df){
          *(s16x8*)((u16*)dout + (size_t)gr * DD + sl * 8) = v;
        } else {
          f32x4 o0, o1;
#pragma unroll
          for (int e = 0; e < 4; e++){ o0[e] = b2f((u16)v[e]); o1[e] = b2f((u16)v[4 + e]); }
          *(f32x4*)((float*)dout + (size_t)gr * DD + sl * 8) = o0;
          *(f32x4*)((float*)dout + (size_t)gr * DD + sl * 8 + 4) = o1;
        }
      } else {
        *(s16x8*)(H + (size_t)gr * DD + sl * 8) = v;
      }
      if (partial){
#pragma unroll
        for (int e = 0; e < 8; e++){
          float f = b2f((u16)v[e]);
          s[e] += f; q[e] += f * f;
        }
      }
    }
  }
  if (partial){
#pragma unroll
    for (int e = 0; e < 8; e++){
      s[e] += __shfl_xor(s[e], 32);
      q[e] += __shfl_xor(q[e], 32);
    }
    __syncthreads();                     // all As/Ms reads done
    float* redS = (float*)Ms;            // 8x256 f32 = 8 KB
    float* redQ = redS + 8 * 256;        // 8x256 f32 = 8 KB (fits 32 KB Ms)
    if (lane < 32){
#pragma unroll
      for (int e = 0; e < 8; e++){
        redS[wave * 256 + sl * 8 + e] = s[e];
        redQ[wave * 256 + sl * 8 + e] = q[e];
      }
    }
    __syncthreads();
    if (tid < 256){
      float a = 0.f, b = 0.f;
#pragma unroll
      for (int w = 0; w < 8; w++){ a += redS[w * 256 + tid]; b += redQ[w * 256 + tid]; }
      partial[(size_t)blockIdx.x * DD + tid] = a;
      partial[(size_t)(npart + blockIdx.x) * DD + tid] = b;
    }
  }
}

// ---------------- BN reduce: sums[which][j] = sum over npart partials ----
__global__ void bn_reduce(const float* __restrict__ partial, float* __restrict__ sums,
                          int npart){
  int b = blockIdx.x, which = b >> 3, jg = b & 7;  // grid = 16
  int t = threadIdx.x;
  int j = jg * 32 + (t >> 3);
  int li = t & 7;
  float s = 0.f;
  for (int i = li; i < npart; i += 8)
    s += partial[(size_t)(which * npart + i) * DD + j];
  s += __shfl_xor(s, 1); s += __shfl_xor(s, 2); s += __shfl_xor(s, 4);
  if (li == 0) sums[which * DD + j] = s;
}

// ---------------- host ----------------
extern "C" void kernel_launch(void* const* d_in, const int* in_sizes, int n_in,
                              void* d_out, int out_size, void* d_ws, size_t ws_size,
                              hipStream_t stream){
  (void)n_in; (void)out_size; (void)ws_size;
  const int* x    = (const int*)d_in[0];
  const int* ei   = (const int*)d_in[1];
  const int* ea   = (const int*)d_in[2];
  const void* xe1 = d_in[3];
  const void* xe2 = d_in[4];
  const void* ee1 = d_in[5];
  const void* ee2 = d_in[6];
  const void* W1  = d_in[7];
  const void* b1  = d_in[8];
  const void* W2  = d_in[9];
  const void* b2  = d_in[10];
  const void* gam = d_in[11];
  const void* bet = d_in[12];

  int N = in_sizes[0] / 2;
  int E = in_sizes[1] / 2;
  int NB = (N + 1023) / 1024;
  const int L = 5;
  int nblk = (N + 63) / 64;        // fused-layer blocks
  int npart = nblk;                // BN partials (one per block)

  // manual workspace carve (256B aligned)
  char* base = (char*)d_ws;
  size_t off = 0;
  u32* flag    = (u32*)(base + off);   off += 256;
  u16* TBL     = (u16*)(base + off);   off += ((size_t)L * 18 * DD * 2 + 255) & ~(size_t)255;
  u16* EMB9    = (u16*)(base + off);   off += ((size_t)9 * DD * 2 + 255) & ~(size_t)255;
  u8* codes    = (u8*)(base + off);    off += ((size_t)N + 255) & ~(size_t)255;
  int* counts  = (int*)(base + off);   off += ((size_t)N * 4 + 255) & ~(size_t)255;
  int* offsets = (int*)(base + off);   off += ((size_t)N * 4 + 255) & ~(size_t)255;
  int* cursor  = (int*)(base + off);   off += ((size_t)N * 4 + 255) & ~(size_t)255;
  int* bsum    = (int*)(base + off);   off += ((size_t)NB * 4 + 255) & ~(size_t)255;
  int* payload = (int*)(base + off);   off += ((size_t)E * 4 + 255) & ~(size_t)255;
  float* part  = (float*)(base + off); off += ((size_t)2 * npart * DD * 4 + 255) & ~(size_t)255;
  float* sums  = (float*)(base + off); off += ((size_t)2 * DD * 4 + 255) & ~(size_t)255;
  // bf16 working copies of float inputs
  u16* wx1  = (u16*)(base + off); off += ((size_t)120 * DD * 2 + 255) & ~(size_t)255;
  u16* wx2  = (u16*)(base + off); off += ((size_t)3 * DD * 2 + 255) & ~(size_t)255;
  u16* wee1 = (u16*)(base + off); off += ((size_t)L * 6 * DD * 2 + 255) & ~(size_t)255;
  u16* wee2 = (u16*)(base + off); off += ((size_t)L * 3 * DD * 2 + 255) & ~(size_t)255;
  u16* wW1  = (u16*)(base + off); off += ((size_t)L * DD * 2 * DD * 2 + 255) & ~(size_t)255;
  u16* wb1  = (u16*)(base + off); off += ((size_t)L * 2 * DD * 2 + 255) & ~(size_t)255;
  u16* wW2  = (u16*)(base + off); off += ((size_t)L * 2 * DD * DD * 2 + 255) & ~(size_t)255;
  u16* wb2  = (u16*)(base + off); off += ((size_t)L * DD * 2 + 255) & ~(size_t)255;
  u16* wgam = (u16*)(base + off); off += ((size_t)(L - 1) * DD * 2 + 255) & ~(size_t)255;
  u16* wbet = (u16*)(base + off); off += ((size_t)(L - 1) * DD * 2 + 255) & ~(size_t)255;
  // packed MFMA B fragments
  u16* Wp1  = (u16*)(base + off); off += ((size_t)L * DD * 2 * DD * 2 + 255) & ~(size_t)255;
  u16* Wp2  = (u16*)(base + off); off += ((size_t)L * 2 * DD * DD * 2 + 255) & ~(size_t)255;
  // ping-pong feature buffers (bf16)
  u16* featA = (u16*)(base + off); off += ((size_t)N * DD * 2 + 255) & ~(size_t)255;
  u16* featB = (u16*)(base + off); off += ((size_t)N * DD * 2 + 255) & ~(size_t)255;

  // dtype probe + batched input conversion to bf16 working copies
  probe_dtype<<<1, 64, 0, stream>>>((const u32*)xe1, flag);
  {
    CvtArgs ca;
    const void* srcs[10] = { xe1, xe2, ee1, ee2, W1, b1, W2, b2, gam, bet };
    u16* dsts[10] = { wx1, wx2, wee1, wee2, wW1, wb1, wW2, wb2, wgam, wbet };
    int ns[10] = { 120 * DD, 3 * DD, L * 6 * DD, L * 3 * DD, L * DD * 2 * DD,
                   L * 2 * DD, L * 2 * DD * DD, L * DD, (L - 1) * DD, (L - 1) * DD };
    int total = 0;
    for (int i = 0; i < 10; i++){ ca.src[i] = srcs[i]; ca.dst[i] = dsts[i]; ca.n[i] = ns[i]; total += ns[i]; }
    cvt_batch<<<(total + 255) / 256, 256, 0, stream>>>(ca, flag);
  }

  // one-time per call: tables, packed weights (batched), CSR
  build_table<<<90, 256, 0, stream>>>(wee1, wee2, TBL);
  build_emb9<<<9, 256, 0, stream>>>(wx1, wx2, EMB9);
  gen_codes<<<(N + 255) / 256, 256, 0, stream>>>(x, codes, N);
  pack_B<<<dim3(64, L), 256, 0, stream>>>(wW1, Wp1, DD, 2 * DD);
  pack_B<<<dim3(64, L), 256, 0, stream>>>(wW2, Wp2, 2 * DD, DD);
  zero_int<<<(N + 255) / 256, 256, 0, stream>>>(counts, N);
  hist_kernel<<<(E + 255) / 256, 256, 0, stream>>>(ei + E, counts, E);
  scan_sums<<<NB, 256, 0, stream>>>(counts, bsum, N);
  scan_top<<<1, 64, 0, stream>>>(bsum, NB);
  scan_block<<<NB, 256, 0, stream>>>(counts, bsum, offsets, cursor, N);
  fill_csr<<<(E + 255) / 256, 256, 0, stream>>>(ei, ea, x, cursor, payload, E);

  float invN = 1.0f / (float)N;
  u16* fin = featA;
  u16* fout = featB;

  for (int l = 0; l < L; l++){
    int last = (l == L - 1);
    layer_fused<<<nblk, 512, 0, stream>>>(
        fin, TBL + (size_t)l * 18 * DD, offsets, counts, payload,
        Wp1 + (size_t)l * DD * 2 * DD, wb1 + (size_t)l * 2 * DD,
        Wp2 + (size_t)l * 2 * DD * DD, wb2 + (size_t)l * DD,
        fout, (l < L - 1) ? part : (float*)nullptr, npart, N,
        sums, wgam + (size_t)(l > 0 ? l - 1 : 0) * DD,
        wbet + (size_t)(l > 0 ? l - 1 : 0) * DD, invN, l > 0 ? 1 : 0,
        EMB9, codes, l == 0 ? 1 : 0,
        last ? d_out : (void*)nullptr, flag);

    if (l < L - 1){
      bn_reduce<<<16, 256, 0, stream>>>(part, sums, npart);
    }
    u16* t = fin; fin = fout; fout = t;
  }
}